// Round 1
// baseline (2287.439 us; speedup 1.0000x reference)
//
#include <hip/hip_runtime.h>
#include <cstddef>

#define NEG_SLOPE 0.2f

__device__ __forceinline__ float leaky(float x) { return x >= 0.f ? x : NEG_SLOPE * x; }

// ---------------------------------------------------------------------------
// Fused GEMM: h = x @ W  (x: [N,128], W: [128,F]), plus alphaS[i] = h[i]·a_s,
// alphaD[i] = h[i]·a_d.  256 threads/block, 32 rows/block, 8 threads/row.
// W staged in LDS in K-tiles of 64; x tile staged once (padded, conflict-free).
// ---------------------------------------------------------------------------
template <int F>
__global__ __launch_bounds__(256) void gemm_alpha(
    const float* __restrict__ x, const float* __restrict__ W,
    const float* __restrict__ a_s, const float* __restrict__ a_d,
    float* __restrict__ h, float* __restrict__ alphaS, float* __restrict__ alphaD,
    int N)
{
    constexpr int K = 128;
    constexpr int BK = 64;
    constexpr int ROWS = 32;
    constexpr int TPR = 8;            // threads per row
    constexpr int CPT = F / TPR;      // cols per thread (16 or 8)
    constexpr int NJ = CPT / 4;       // float4 groups per thread (4 or 2)

    __shared__ float Ws[BK * F];          // 32KB (F=128) / 16KB (F=64)
    __shared__ float xs[ROWS][K + 4];     // padded: conflict-free row reads

    const int tid = threadIdx.x;
    const int row0 = blockIdx.x * ROWS;

    // stage x tile (float4, coalesced)
    for (int i = tid; i < ROWS * (K / 4); i += 256) {
        int r = i / (K / 4), c4 = i % (K / 4);
        int gr = row0 + r;
        float4 v = (gr < N) ? *(const float4*)(x + (size_t)gr * K + c4 * 4)
                            : make_float4(0.f, 0.f, 0.f, 0.f);
        *(float4*)(&xs[r][c4 * 4]) = v;
    }

    const int rl = tid / TPR;   // local row
    const int cq = tid % TPR;   // col-quad index (lanes 0..7 -> banks spread)

    float acc[CPT];
#pragma unroll
    for (int i = 0; i < CPT; i++) acc[i] = 0.f;

    for (int kt = 0; kt < K / BK; kt++) {
        __syncthreads();
        // stage W k-tile
        for (int i = tid * 4; i < BK * F; i += 256 * 4)
            *(float4*)(Ws + i) = *(const float4*)(W + kt * BK * F + i);
        __syncthreads();

#pragma unroll 8
        for (int k = 0; k < BK; k++) {
            float xk = xs[rl][kt * BK + k];
#pragma unroll
            for (int j = 0; j < NJ; j++) {
                float4 wv = *(const float4*)(Ws + k * F + cq * 4 + j * 32);
                acc[j * 4 + 0] += xk * wv.x;
                acc[j * 4 + 1] += xk * wv.y;
                acc[j * 4 + 2] += xk * wv.z;
                acc[j * 4 + 3] += xk * wv.w;
            }
        }
    }

    const int gr = row0 + rl;
    if (gr < N) {
        float ps = 0.f, pd = 0.f;
#pragma unroll
        for (int j = 0; j < NJ; j++) {
            int c = cq * 4 + j * 32;
            float4 av = make_float4(acc[j * 4], acc[j * 4 + 1], acc[j * 4 + 2], acc[j * 4 + 3]);
            *(float4*)(h + (size_t)gr * F + c) = av;
            float4 sv = *(const float4*)(a_s + c);
            float4 dv = *(const float4*)(a_d + c);
            ps += av.x * sv.x + av.y * sv.y + av.z * sv.z + av.w * sv.w;
            pd += av.x * dv.x + av.y * dv.y + av.z * dv.z + av.w * dv.w;
        }
        // reduce over the 8 consecutive lanes of this row
        ps += __shfl_down(ps, 4, 8); pd += __shfl_down(pd, 4, 8);
        ps += __shfl_down(ps, 2, 8); pd += __shfl_down(pd, 2, 8);
        ps += __shfl_down(ps, 1, 8); pd += __shfl_down(pd, 1, 8);
        if (cq == 0) { alphaS[gr] = ps; alphaD[gr] = pd; }
    }
}

// ---------------------------------------------------------------------------
// Edge scores: w[e] = exp(leaky(aS[src]+aD[dst])), denom[dst] += w[e].
// (segment_max skipped: softmax is shift-invariant; scores are O(10), safe.)
// ---------------------------------------------------------------------------
__global__ __launch_bounds__(256) void edge_scores(
    const int* __restrict__ src, const int* __restrict__ dst,
    const float* __restrict__ aS, const float* __restrict__ aD,
    float* __restrict__ w, float* __restrict__ denom, int E)
{
    int e = blockIdx.x * 256 + threadIdx.x;
    if (e < E) {
        int s = src[e], d = dst[e];
        float we = __expf(leaky(aS[s] + aD[d]));
        w[e] = we;
        unsafeAtomicAdd(denom + d, we);
    }
}

// ---------------------------------------------------------------------------
// acc[dst] += w[e] * h[src] ; F/4 lanes per edge, float4 gather, scalar atomics
// ---------------------------------------------------------------------------
template <int F>
__global__ __launch_bounds__(256) void aggregate(
    const int* __restrict__ src, const int* __restrict__ dst,
    const float* __restrict__ w, const float* __restrict__ h,
    float* __restrict__ acc, int E)
{
    constexpr int LPE = F / 4;
    int gid = blockIdx.x * 256 + threadIdx.x;
    int e = gid / LPE;
    int l = gid % LPE;
    if (e < E) {
        int s = src[e], d = dst[e];
        float we = w[e];
        float4 hv = *(const float4*)(h + (size_t)s * F + l * 4);
        float* ap = acc + (size_t)d * F + l * 4;
        unsafeAtomicAdd(ap + 0, we * hv.x);
        unsafeAtomicAdd(ap + 1, we * hv.y);
        unsafeAtomicAdd(ap + 2, we * hv.z);
        unsafeAtomicAdd(ap + 3, we * hv.w);
    }
}

// ---------------------------------------------------------------------------
// out[i] = (acc[i] + w_self*h[i]) / (denom[i] + w_self) + bias  [; relu]
// Self-loop folded in analytically (w_self = exp(leaky(aS[i]+aD[i]))).
// Safe in-place (out may alias acc).
// ---------------------------------------------------------------------------
template <int F, bool RELU>
__global__ __launch_bounds__(256) void finalize(
    const float* __restrict__ acc, const float* __restrict__ denom,
    const float* __restrict__ h, const float* __restrict__ aS,
    const float* __restrict__ aD, const float* __restrict__ bias,
    float* __restrict__ out, int N)
{
    constexpr int LPN = F / 4;
    int gid = blockIdx.x * 256 + threadIdx.x;
    int i = gid / LPN;
    int l = gid % LPN;
    if (i < N) {
        float wsf = __expf(leaky(aS[i] + aD[i]));
        float inv = 1.f / (denom[i] + wsf);
        float4 av = *(const float4*)(acc + (size_t)i * F + l * 4);
        float4 hv = *(const float4*)(h + (size_t)i * F + l * 4);
        float4 bv = *(const float4*)(bias + l * 4);
        float4 o;
        o.x = (av.x + wsf * hv.x) * inv + bv.x;
        o.y = (av.y + wsf * hv.y) * inv + bv.y;
        o.z = (av.z + wsf * hv.z) * inv + bv.z;
        o.w = (av.w + wsf * hv.w) * inv + bv.w;
        if (RELU) {
            o.x = fmaxf(o.x, 0.f); o.y = fmaxf(o.y, 0.f);
            o.z = fmaxf(o.z, 0.f); o.w = fmaxf(o.w, 0.f);
        }
        *(float4*)(out + (size_t)i * F + l * 4) = o;
    }
}

extern "C" void kernel_launch(void* const* d_in, const int* in_sizes, int n_in,
                              void* d_out, int out_size, void* d_ws, size_t ws_size,
                              hipStream_t stream)
{
    const float* x   = (const float*)d_in[0];
    const int*   ei  = (const int*)d_in[1];
    const float* W1  = (const float*)d_in[2];
    const float* aS1 = (const float*)d_in[3];
    const float* aD1 = (const float*)d_in[4];
    const float* b1  = (const float*)d_in[5];
    const float* W2  = (const float*)d_in[6];
    const float* aS2 = (const float*)d_in[7];
    const float* aD2 = (const float*)d_in[8];
    const float* b2  = (const float*)d_in[9];

    const int K = 128, F1 = 128, F2 = 64;
    const int N = in_sizes[0] / K;
    const int E = in_sizes[1] / 2;
    const int* src = ei;
    const int* dst = ei + E;

    // workspace layout (floats). Zero-init region first (re-poisoned each call).
    float* ws = (float*)d_ws;
    float* acc1 = ws; ws += (size_t)N * F1;   // reused as x2 after finalize1 (in-place)
    float* acc2 = ws; ws += (size_t)N * F2;
    float* den1 = ws; ws += N;
    float* den2 = ws; ws += N;
    const size_t zbytes = (size_t)N * (F1 + F2 + 2) * sizeof(float);
    float* h1  = ws; ws += (size_t)N * F1;
    float* h2  = ws; ws += (size_t)N * F2;
    float* as_ = ws; ws += N;
    float* ad_ = ws; ws += N;
    float* wE  = ws; ws += E;

    hipMemsetAsync(acc1, 0, zbytes, stream);

    dim3 blk(256);

    // ---- layer 1 ----
    gemm_alpha<F1><<<dim3((N + 31) / 32), blk, 0, stream>>>(x, W1, aS1, aD1, h1, as_, ad_, N);
    edge_scores<<<dim3((E + 255) / 256), blk, 0, stream>>>(src, dst, as_, ad_, wE, den1, E);
    aggregate<F1><<<dim3((E * (F1 / 4) + 255) / 256), blk, 0, stream>>>(src, dst, wE, h1, acc1, E);
    finalize<F1, true><<<dim3((N * (F1 / 4) + 255) / 256), blk, 0, stream>>>(
        acc1, den1, h1, as_, ad_, b1, acc1, N);

    // ---- layer 2 (input x2 == acc1) ----
    gemm_alpha<F2><<<dim3((N + 31) / 32), blk, 0, stream>>>(acc1, W2, aS2, aD2, h2, as_, ad_, N);
    edge_scores<<<dim3((E + 255) / 256), blk, 0, stream>>>(src, dst, as_, ad_, wE, den2, E);
    aggregate<F2><<<dim3((E * (F2 / 4) + 255) / 256), blk, 0, stream>>>(src, dst, wE, h2, acc2, E);
    finalize<F2, false><<<dim3((N * (F2 / 4) + 255) / 256), blk, 0, stream>>>(
        acc2, den2, h2, as_, ad_, b2, (float*)d_out, N);
}

// Round 2
// 392.931 us; speedup vs baseline: 5.8215x; 5.8215x over previous
//
#include <hip/hip_runtime.h>
#include <cstddef>

#define NEG_SLOPE 0.2f

__device__ __forceinline__ float leaky(float x) { return x >= 0.f ? x : NEG_SLOPE * x; }

// ---------------------------------------------------------------------------
// Fused GEMM: h = x @ W  (x: [N,128], W: [128,F]), plus alphaS[i] = h[i]·a_s,
// alphaD[i] = h[i]·a_d.  256 threads/block, 32 rows/block, 8 threads/row.
// ---------------------------------------------------------------------------
template <int F>
__global__ __launch_bounds__(256) void gemm_alpha(
    const float* __restrict__ x, const float* __restrict__ W,
    const float* __restrict__ a_s, const float* __restrict__ a_d,
    float* __restrict__ h, float* __restrict__ alphaS, float* __restrict__ alphaD,
    int N)
{
    constexpr int K = 128;
    constexpr int BK = 64;
    constexpr int ROWS = 32;
    constexpr int TPR = 8;
    constexpr int CPT = F / TPR;
    constexpr int NJ = CPT / 4;

    __shared__ float Ws[BK * F];
    __shared__ float xs[ROWS][K + 4];

    const int tid = threadIdx.x;
    const int row0 = blockIdx.x * ROWS;

    for (int i = tid; i < ROWS * (K / 4); i += 256) {
        int r = i / (K / 4), c4 = i % (K / 4);
        int gr = row0 + r;
        float4 v = (gr < N) ? *(const float4*)(x + (size_t)gr * K + c4 * 4)
                            : make_float4(0.f, 0.f, 0.f, 0.f);
        *(float4*)(&xs[r][c4 * 4]) = v;
    }

    const int rl = tid / TPR;
    const int cq = tid % TPR;

    float acc[CPT];
#pragma unroll
    for (int i = 0; i < CPT; i++) acc[i] = 0.f;

    for (int kt = 0; kt < K / BK; kt++) {
        __syncthreads();
        for (int i = tid * 4; i < BK * F; i += 256 * 4)
            *(float4*)(Ws + i) = *(const float4*)(W + kt * BK * F + i);
        __syncthreads();

#pragma unroll 8
        for (int k = 0; k < BK; k++) {
            float xk = xs[rl][kt * BK + k];
#pragma unroll
            for (int j = 0; j < NJ; j++) {
                float4 wv = *(const float4*)(Ws + k * F + cq * 4 + j * 32);
                acc[j * 4 + 0] += xk * wv.x;
                acc[j * 4 + 1] += xk * wv.y;
                acc[j * 4 + 2] += xk * wv.z;
                acc[j * 4 + 3] += xk * wv.w;
            }
        }
    }

    const int gr = row0 + rl;
    if (gr < N) {
        float ps = 0.f, pd = 0.f;
#pragma unroll
        for (int j = 0; j < NJ; j++) {
            int c = cq * 4 + j * 32;
            float4 av = make_float4(acc[j * 4], acc[j * 4 + 1], acc[j * 4 + 2], acc[j * 4 + 3]);
            *(float4*)(h + (size_t)gr * F + c) = av;
            float4 sv = *(const float4*)(a_s + c);
            float4 dv = *(const float4*)(a_d + c);
            ps += av.x * sv.x + av.y * sv.y + av.z * sv.z + av.w * sv.w;
            pd += av.x * dv.x + av.y * dv.y + av.z * dv.z + av.w * dv.w;
        }
        ps += __shfl_down(ps, 4, 8); pd += __shfl_down(pd, 4, 8);
        ps += __shfl_down(ps, 2, 8); pd += __shfl_down(pd, 2, 8);
        ps += __shfl_down(ps, 1, 8); pd += __shfl_down(pd, 1, 8);
        if (cq == 0) { alphaS[gr] = ps; alphaD[gr] = pd; }
    }
}

// ---------------------------------------------------------------------------
// CSR build: histogram of dst, exclusive scan -> rowptr + fill, scatter src.
// ---------------------------------------------------------------------------
__global__ __launch_bounds__(256) void hist_kernel(
    const int* __restrict__ dst, int* __restrict__ cnt, int E)
{
    int e = blockIdx.x * 256 + threadIdx.x;
    if (e < E) atomicAdd(cnt + dst[e], 1);
}

__global__ __launch_bounds__(1024) void exscan_kernel(
    const int* __restrict__ cnt, int* __restrict__ rowptr,
    int* __restrict__ fill, int N)
{
    __shared__ int wsum[16];
    __shared__ int carry_s;
    const int tid = threadIdx.x;
    if (tid == 0) carry_s = 0;
    __syncthreads();
    for (int base = 0; base < N; base += 1024) {
        int idx = base + tid;
        int v = (idx < N) ? cnt[idx] : 0;
        int incl = v;
#pragma unroll
        for (int off = 1; off < 64; off <<= 1) {
            int t = __shfl_up(incl, off);
            if ((tid & 63) >= off) incl += t;
        }
        if ((tid & 63) == 63) wsum[tid >> 6] = incl;
        __syncthreads();
        if (tid < 16) {
            int t = wsum[tid];
#pragma unroll
            for (int off = 1; off < 16; off <<= 1) {
                int u = __shfl_up(t, off, 16);
                if (tid >= off) t += u;
            }
            wsum[tid] = t;
        }
        __syncthreads();
        int waveoff = (tid >> 6) == 0 ? 0 : wsum[(tid >> 6) - 1];
        int excl = carry_s + waveoff + incl - v;
        if (idx < N) { rowptr[idx] = excl; fill[idx] = excl; }
        __syncthreads();
        if (tid == 1023) carry_s += wsum[15];
        __syncthreads();
    }
    if (tid == 0) rowptr[N] = carry_s;
}

__global__ __launch_bounds__(256) void scatter_kernel(
    const int* __restrict__ src, const int* __restrict__ dst,
    int* __restrict__ fill, int* __restrict__ src_sorted, int E)
{
    int e = blockIdx.x * 256 + threadIdx.x;
    if (e < E) {
        int p = atomicAdd(fill + dst[e], 1);
        src_sorted[p] = src[e];
    }
}

// ---------------------------------------------------------------------------
// Fused per-destination aggregation (no atomics):
//   out[i] = (sum_e w_e h[src_e] + w_self h[i]) / (sum_e w_e + w_self) + b
// One wave per node; EPW = 64/(F/4) edges in flight per wave.
// ---------------------------------------------------------------------------
template <int F, bool RELU>
__global__ __launch_bounds__(256) void gat_aggregate(
    const int* __restrict__ rowptr, const int* __restrict__ src_sorted,
    const float* __restrict__ h, const float* __restrict__ aS,
    const float* __restrict__ aD, const float* __restrict__ bias,
    float* __restrict__ out, int N)
{
    constexpr int LPE = F / 4;          // lanes per edge (32 or 16)
    constexpr int EPW = 64 / LPE;       // edge slots per wave (2 or 4)

    const int wave = blockIdx.x * 4 + (threadIdx.x >> 6);
    if (wave >= N) return;
    const int i = wave;
    const int lane = threadIdx.x & 63;
    const int sub = lane / LPE;         // edge slot
    const int l = lane % LPE;           // float4 index within feature row

    const float adi = aD[i];
    const int start = rowptr[i];
    const int end = rowptr[i + 1];

    float4 acc = make_float4(0.f, 0.f, 0.f, 0.f);
    float denom = 0.f;

    for (int e = start + sub; e < end; e += EPW) {
        int s = src_sorted[e];                       // broadcast across LPE lanes
        float w = __expf(leaky(aS[s] + adi));
        float4 hv = *(const float4*)(h + (size_t)s * F + l * 4);
        acc.x += w * hv.x; acc.y += w * hv.y;
        acc.z += w * hv.z; acc.w += w * hv.w;
        denom += w;
    }

    // reduce edge slots down to lanes [0, LPE)
#pragma unroll
    for (int off = 32; off >= LPE; off >>= 1) {
        acc.x += __shfl_down(acc.x, off);
        acc.y += __shfl_down(acc.y, off);
        acc.z += __shfl_down(acc.z, off);
        acc.w += __shfl_down(acc.w, off);
        denom += __shfl_down(denom, off);
    }

    if (sub == 0) {
        float wsf = __expf(leaky(aS[i] + adi));
        float4 hv = *(const float4*)(h + (size_t)i * F + l * 4);
        float inv = 1.f / (denom + wsf);
        float4 bv = *(const float4*)(bias + l * 4);
        float4 o;
        o.x = (acc.x + wsf * hv.x) * inv + bv.x;
        o.y = (acc.y + wsf * hv.y) * inv + bv.y;
        o.z = (acc.z + wsf * hv.z) * inv + bv.z;
        o.w = (acc.w + wsf * hv.w) * inv + bv.w;
        if (RELU) {
            o.x = fmaxf(o.x, 0.f); o.y = fmaxf(o.y, 0.f);
            o.z = fmaxf(o.z, 0.f); o.w = fmaxf(o.w, 0.f);
        }
        *(float4*)(out + (size_t)i * F + l * 4) = o;
    }
}

extern "C" void kernel_launch(void* const* d_in, const int* in_sizes, int n_in,
                              void* d_out, int out_size, void* d_ws, size_t ws_size,
                              hipStream_t stream)
{
    const float* x   = (const float*)d_in[0];
    const int*   ei  = (const int*)d_in[1];
    const float* W1  = (const float*)d_in[2];
    const float* aS1 = (const float*)d_in[3];
    const float* aD1 = (const float*)d_in[4];
    const float* b1  = (const float*)d_in[5];
    const float* W2  = (const float*)d_in[6];
    const float* aS2 = (const float*)d_in[7];
    const float* aD2 = (const float*)d_in[8];
    const float* b2  = (const float*)d_in[9];

    const int K = 128, F1 = 128, F2 = 64;
    const int N = in_sizes[0] / K;
    const int E = in_sizes[1] / 2;
    const int* src = ei;
    const int* dst = ei + E;

    const int Np = (N + 4) & ~3;   // padded for 16B alignment of later buffers

    // workspace layout (4-byte elems, all 16B-aligned)
    char* wsb = (char*)d_ws;
    int* cnt        = (int*)wsb;                 wsb += (size_t)Np * 4;   // zeroed
    int* rowptr     = (int*)wsb;                 wsb += (size_t)(Np + 4) * 4;
    int* fill       = (int*)wsb;                 wsb += (size_t)Np * 4;
    int* src_sorted = (int*)wsb;                 wsb += (size_t)E * 4;
    float* h1       = (float*)wsb;               wsb += (size_t)N * F1 * 4;
    float* x2       = (float*)wsb;               wsb += (size_t)N * F1 * 4;
    float* h2       = (float*)wsb;               wsb += (size_t)N * F2 * 4;
    float* as_      = (float*)wsb;               wsb += (size_t)Np * 4;
    float* ad_      = (float*)wsb;               wsb += (size_t)Np * 4;

    hipMemsetAsync(cnt, 0, (size_t)Np * 4, stream);

    dim3 blk(256);

    // ---- CSR build (dst-sorted edge permutation) ----
    hist_kernel<<<dim3((E + 255) / 256), blk, 0, stream>>>(dst, cnt, E);
    exscan_kernel<<<dim3(1), dim3(1024), 0, stream>>>(cnt, rowptr, fill, N);
    scatter_kernel<<<dim3((E + 255) / 256), blk, 0, stream>>>(src, dst, fill, src_sorted, E);

    // ---- layer 1 ----
    gemm_alpha<F1><<<dim3((N + 31) / 32), blk, 0, stream>>>(x, W1, aS1, aD1, h1, as_, ad_, N);
    gat_aggregate<F1, true><<<dim3((N + 3) / 4), blk, 0, stream>>>(
        rowptr, src_sorted, h1, as_, ad_, b1, x2, N);

    // ---- layer 2 ----
    gemm_alpha<F2><<<dim3((N + 31) / 32), blk, 0, stream>>>(x2, W2, aS2, aD2, h2, as_, ad_, N);
    gat_aggregate<F2, false><<<dim3((N + 3) / 4), blk, 0, stream>>>(
        rowptr, src_sorted, h2, as_, ad_, b2, (float*)d_out, N);
}

// Round 3
// 344.172 us; speedup vs baseline: 6.6462x; 1.1417x over previous
//
#include <hip/hip_runtime.h>
#include <cstddef>

#define NEG_SLOPE 0.2f

__device__ __forceinline__ float leaky(float x) { return x >= 0.f ? x : NEG_SLOPE * x; }

__device__ __forceinline__ int wave_iscan(int v, int lane) {
#pragma unroll
    for (int off = 1; off < 64; off <<= 1) {
        int t = __shfl_up(v, off);
        if (lane >= off) v += t;
    }
    return v;
}

// ---------------------------------------------------------------------------
// Register-blocked SGEMM + fused alpha dot products.
// h = x @ W   (x: [N,128] row-major, W: [128,F] row-major)
// Block tile: 128 rows x F cols. Thread tile: 8x8. Threads: 16 * (F/8).
// As holds the x-tile transposed (k-major) so row reads are contiguous b128.
// ---------------------------------------------------------------------------
template <int F>
__global__ __launch_bounds__(256) void gemm_alpha(
    const float* __restrict__ x, const float* __restrict__ W,
    const float* __restrict__ a_s, const float* __restrict__ a_d,
    float* __restrict__ h, float* __restrict__ alphaS, float* __restrict__ alphaD,
    int N)
{
    constexpr int K = 128;
    constexpr int BK = 16;
    constexpr int BM = 128;
    constexpr int TM = 8;
    constexpr int TN = 8;
    constexpr int TC = F / TN;            // thread-cols (16 or 8)
    constexpr int THREADS = 16 * TC;      // 256 (F=128) or 128 (F=64)

    __shared__ float As[BK][BM + 4];      // transposed x tile
    __shared__ float Bs[BK][F + 4];       // W tile

    const int tid = threadIdx.x;
    const int tr = tid / TC;              // 0..15
    const int tc = tid % TC;              // 0..TC-1
    const int rowb = blockIdx.x * BM;
    const int col0 = tc * TN;

    float acc[TM][TN];
#pragma unroll
    for (int m = 0; m < TM; m++)
#pragma unroll
        for (int n = 0; n < TN; n++) acc[m][n] = 0.f;

    for (int kt = 0; kt < K / BK; kt++) {
        // stage x tile transposed: BM x BK floats
        for (int i = tid; i < BM * (BK / 4); i += THREADS) {
            int r = i >> 2, c4 = i & 3;
            int gr = rowb + r;
            float4 v = (gr < N) ? *(const float4*)(x + (size_t)gr * K + kt * BK + c4 * 4)
                                : make_float4(0.f, 0.f, 0.f, 0.f);
            As[c4 * 4 + 0][r] = v.x;
            As[c4 * 4 + 1][r] = v.y;
            As[c4 * 4 + 2][r] = v.z;
            As[c4 * 4 + 3][r] = v.w;
        }
        // stage W tile: BK x F floats
        for (int i = tid; i < BK * (F / 4); i += THREADS) {
            int r = i / (F / 4), c4 = i % (F / 4);
            *(float4*)&Bs[r][c4 * 4] = *(const float4*)(W + (size_t)(kt * BK + r) * F + c4 * 4);
        }
        __syncthreads();

#pragma unroll
        for (int k = 0; k < BK; k++) {
            float a[TM], b[TN];
            *(float4*)&a[0] = *(float4*)&As[k][tr * TM];
            *(float4*)&a[4] = *(float4*)&As[k][tr * TM + 4];
            *(float4*)&b[0] = *(float4*)&Bs[k][col0];
            *(float4*)&b[4] = *(float4*)&Bs[k][col0 + 4];
#pragma unroll
            for (int m = 0; m < TM; m++)
#pragma unroll
                for (int n = 0; n < TN; n++)
                    acc[m][n] += a[m] * b[n];
        }
        __syncthreads();
    }

    // epilogue: store h, fused alpha partial dots + shfl reduce across tc group
    float asv[TN], adv[TN];
    *(float4*)&asv[0] = *(const float4*)(a_s + col0);
    *(float4*)&asv[4] = *(const float4*)(a_s + col0 + 4);
    *(float4*)&adv[0] = *(const float4*)(a_d + col0);
    *(float4*)&adv[4] = *(const float4*)(a_d + col0 + 4);

#pragma unroll
    for (int m = 0; m < TM; m++) {
        int row = rowb + tr * TM + m;
        bool ok = (row < N);
        if (ok) {
            *(float4*)(h + (size_t)row * F + col0)     = make_float4(acc[m][0], acc[m][1], acc[m][2], acc[m][3]);
            *(float4*)(h + (size_t)row * F + col0 + 4) = make_float4(acc[m][4], acc[m][5], acc[m][6], acc[m][7]);
        }
        float ps = 0.f, pd = 0.f;
#pragma unroll
        for (int n = 0; n < TN; n++) {
            ps += acc[m][n] * asv[n];
            pd += acc[m][n] * adv[n];
        }
#pragma unroll
        for (int off = TC / 2; off >= 1; off >>= 1) {
            ps += __shfl_down(ps, off, TC);
            pd += __shfl_down(pd, off, TC);
        }
        if (ok && tc == 0) { alphaS[row] = ps; alphaD[row] = pd; }
    }
}

// ---------------------------------------------------------------------------
// CSR build: histogram, multi-block exclusive scan, scatter permutation.
// ---------------------------------------------------------------------------
__global__ __launch_bounds__(256) void hist_kernel(
    const int* __restrict__ dst, int* __restrict__ cnt, int E)
{
    int e = blockIdx.x * 256 + threadIdx.x;
    if (e < E) atomicAdd(cnt + dst[e], 1);
}

__global__ __launch_bounds__(256) void scan_bsum(
    const int* __restrict__ cnt, int* __restrict__ bsum, int N)
{
    int i = blockIdx.x * 256 + threadIdx.x;
    int v = (i < N) ? cnt[i] : 0;
#pragma unroll
    for (int off = 32; off; off >>= 1) v += __shfl_down(v, off);
    __shared__ int ws[4];
    int lane = threadIdx.x & 63, wid = threadIdx.x >> 6;
    if (lane == 0) ws[wid] = v;
    __syncthreads();
    if (threadIdx.x == 0) bsum[blockIdx.x] = ws[0] + ws[1] + ws[2] + ws[3];
}

__global__ __launch_bounds__(256) void scan_boff(
    const int* __restrict__ bsum, int* __restrict__ boff, int nb, int* __restrict__ totptr)
{
    __shared__ int ws[4];
    __shared__ int carry;
    int tid = threadIdx.x, lane = tid & 63, wid = tid >> 6;
    if (tid == 0) carry = 0;
    __syncthreads();
    for (int base = 0; base < nb; base += 256) {
        int i = base + tid;
        int v = (i < nb) ? bsum[i] : 0;
        int incl = wave_iscan(v, lane);
        if (lane == 63) ws[wid] = incl;
        __syncthreads();
        int woff = carry;
        for (int w = 0; w < wid; w++) woff += ws[w];
        if (i < nb) boff[i] = woff + incl - v;
        __syncthreads();
        if (tid == 0) carry += ws[0] + ws[1] + ws[2] + ws[3];
        __syncthreads();
    }
    if (tid == 0) *totptr = carry;
}

__global__ __launch_bounds__(256) void scan_final(
    const int* __restrict__ cnt, const int* __restrict__ boff,
    int* __restrict__ rowptr, int* __restrict__ fill, int N)
{
    int i = blockIdx.x * 256 + threadIdx.x;
    int v = (i < N) ? cnt[i] : 0;
    int lane = threadIdx.x & 63, wid = threadIdx.x >> 6;
    int incl = wave_iscan(v, lane);
    __shared__ int ws[4];
    if (lane == 63) ws[wid] = incl;
    __syncthreads();
    int woff = boff[blockIdx.x];
    for (int w = 0; w < wid; w++) woff += ws[w];
    int excl = woff + incl - v;
    if (i < N) { rowptr[i] = excl; fill[i] = excl; }
}

__global__ __launch_bounds__(256) void scatter_kernel(
    const int* __restrict__ src, const int* __restrict__ dst,
    int* __restrict__ fill, int* __restrict__ src_sorted, int E)
{
    int e = blockIdx.x * 256 + threadIdx.x;
    if (e < E) {
        int p = atomicAdd(fill + dst[e], 1);
        src_sorted[p] = src[e];
    }
}

// ---------------------------------------------------------------------------
// Fused per-destination aggregation (no atomics), 2-wide edge unroll with
// cross-iteration src-index prefetch for memory-level parallelism.
// ---------------------------------------------------------------------------
template <int F, bool RELU>
__global__ __launch_bounds__(256) void gat_aggregate(
    const int* __restrict__ rowptr, const int* __restrict__ src_sorted,
    const float* __restrict__ h, const float* __restrict__ aS,
    const float* __restrict__ aD, const float* __restrict__ bias,
    float* __restrict__ out, int N)
{
    constexpr int LPE = F / 4;          // lanes per edge (32 or 16)
    constexpr int EPW = 64 / LPE;       // edge slots per wave (2 or 4)

    const int i = blockIdx.x * 4 + (threadIdx.x >> 6);
    if (i >= N) return;
    const int lane = threadIdx.x & 63;
    const int sub = lane / LPE;
    const int l = lane % LPE;

    const float adi = aD[i];
    const int start = rowptr[i];
    const int end = rowptr[i + 1];

    float4 acc0 = make_float4(0.f, 0.f, 0.f, 0.f);
    float4 acc1 = make_float4(0.f, 0.f, 0.f, 0.f);
    float den0 = 0.f, den1 = 0.f;

    int e0 = start + sub;
    int e1 = e0 + EPW;
    int s0 = (e0 < end) ? src_sorted[e0] : -1;
    int s1 = (e1 < end) ? src_sorted[e1] : -1;

    while (e0 < end) {
        int n0 = (e0 + 2 * EPW < end) ? src_sorted[e0 + 2 * EPW] : -1;
        int n1 = (e1 + 2 * EPW < end) ? src_sorted[e1 + 2 * EPW] : -1;
        {
            float w = __expf(leaky(aS[s0] + adi));
            float4 hv = *(const float4*)(h + (size_t)s0 * F + l * 4);
            acc0.x += w * hv.x; acc0.y += w * hv.y;
            acc0.z += w * hv.z; acc0.w += w * hv.w;
            den0 += w;
        }
        if (s1 >= 0) {
            float w = __expf(leaky(aS[s1] + adi));
            float4 hv = *(const float4*)(h + (size_t)s1 * F + l * 4);
            acc1.x += w * hv.x; acc1.y += w * hv.y;
            acc1.z += w * hv.z; acc1.w += w * hv.w;
            den1 += w;
        }
        e0 += 2 * EPW; e1 += 2 * EPW;
        s0 = n0; s1 = n1;
        if (s0 < 0) break;
    }

    float4 acc = make_float4(acc0.x + acc1.x, acc0.y + acc1.y,
                             acc0.z + acc1.z, acc0.w + acc1.w);
    float denom = den0 + den1;

#pragma unroll
    for (int off = 32; off >= LPE; off >>= 1) {
        acc.x += __shfl_down(acc.x, off);
        acc.y += __shfl_down(acc.y, off);
        acc.z += __shfl_down(acc.z, off);
        acc.w += __shfl_down(acc.w, off);
        denom += __shfl_down(denom, off);
    }

    if (sub == 0) {
        float wsf = __expf(leaky(aS[i] + adi));
        float4 hv = *(const float4*)(h + (size_t)i * F + l * 4);
        float inv = 1.f / (denom + wsf);
        float4 bv = *(const float4*)(bias + l * 4);
        float4 o;
        o.x = (acc.x + wsf * hv.x) * inv + bv.x;
        o.y = (acc.y + wsf * hv.y) * inv + bv.y;
        o.z = (acc.z + wsf * hv.z) * inv + bv.z;
        o.w = (acc.w + wsf * hv.w) * inv + bv.w;
        if (RELU) {
            o.x = fmaxf(o.x, 0.f); o.y = fmaxf(o.y, 0.f);
            o.z = fmaxf(o.z, 0.f); o.w = fmaxf(o.w, 0.f);
        }
        *(float4*)(out + (size_t)i * F + l * 4) = o;
    }
}

extern "C" void kernel_launch(void* const* d_in, const int* in_sizes, int n_in,
                              void* d_out, int out_size, void* d_ws, size_t ws_size,
                              hipStream_t stream)
{
    const float* x   = (const float*)d_in[0];
    const int*   ei  = (const int*)d_in[1];
    const float* W1  = (const float*)d_in[2];
    const float* aS1 = (const float*)d_in[3];
    const float* aD1 = (const float*)d_in[4];
    const float* b1  = (const float*)d_in[5];
    const float* W2  = (const float*)d_in[6];
    const float* aS2 = (const float*)d_in[7];
    const float* aD2 = (const float*)d_in[8];
    const float* b2  = (const float*)d_in[9];

    const int K = 128, F1 = 128, F2 = 64;
    const int N = in_sizes[0] / K;
    const int E = in_sizes[1] / 2;
    const int* src = ei;
    const int* dst = ei + E;

    const int Np = (N + 4) & ~3;
    const int nb = (N + 255) / 256;

    char* wsb = (char*)d_ws;
    int* cnt        = (int*)wsb;   wsb += (size_t)Np * 4;          // zeroed
    int* rowptr     = (int*)wsb;   wsb += (size_t)(Np + 4) * 4;
    int* fill       = (int*)wsb;   wsb += (size_t)Np * 4;
    int* bsum       = (int*)wsb;   wsb += 1024 * 4;
    int* boff       = (int*)wsb;   wsb += 1024 * 4;
    int* src_sorted = (int*)wsb;   wsb += (size_t)E * 4;
    float* h1       = (float*)wsb; wsb += (size_t)N * F1 * 4;
    float* x2       = (float*)wsb; wsb += (size_t)N * F1 * 4;
    float* h2       = (float*)wsb; wsb += (size_t)N * F2 * 4;
    float* as_      = (float*)wsb; wsb += (size_t)Np * 4;
    float* ad_      = (float*)wsb; wsb += (size_t)Np * 4;

    hipMemsetAsync(cnt, 0, (size_t)Np * 4, stream);

    dim3 blk(256);

    // ---- CSR build ----
    hist_kernel<<<dim3((E + 255) / 256), blk, 0, stream>>>(dst, cnt, E);
    scan_bsum<<<dim3(nb), blk, 0, stream>>>(cnt, bsum, N);
    scan_boff<<<dim3(1), blk, 0, stream>>>(bsum, boff, nb, rowptr + N);
    scan_final<<<dim3(nb), blk, 0, stream>>>(cnt, boff, rowptr, fill, N);
    scatter_kernel<<<dim3((E + 255) / 256), blk, 0, stream>>>(src, dst, fill, src_sorted, E);

    // ---- layer 1 ----
    gemm_alpha<F1><<<dim3((N + 127) / 128), dim3(256), 0, stream>>>(
        x, W1, aS1, aD1, h1, as_, ad_, N);
    gat_aggregate<F1, true><<<dim3((N + 3) / 4), blk, 0, stream>>>(
        rowptr, src_sorted, h1, as_, ad_, b1, x2, N);

    // ---- layer 2 ----
    gemm_alpha<F2><<<dim3((N + 127) / 128), dim3(128), 0, stream>>>(
        x2, W2, aS2, aD2, h2, as_, ad_, N);
    gat_aggregate<F2, false><<<dim3((N + 3) / 4), blk, 0, stream>>>(
        rowptr, src_sorted, h2, as_, ad_, b2, (float*)d_out, N);
}

// Round 4
// 295.396 us; speedup vs baseline: 7.7436x; 1.1651x over previous
//
#include <hip/hip_runtime.h>
#include <hip/hip_fp16.h>
#include <cstddef>

#define NEG_SLOPE 0.2f

__device__ __forceinline__ float leaky(float x) { return x >= 0.f ? x : NEG_SLOPE * x; }

__device__ __forceinline__ int wave_iscan(int v, int lane) {
#pragma unroll
    for (int off = 1; off < 64; off <<= 1) {
        int t = __shfl_up(v, off);
        if (lane >= off) v += t;
    }
    return v;
}

// ---------------------------------------------------------------------------
// Register-blocked SGEMM + fused alpha dots, fp16 output for message gather.
// h = x @ W  (x: [N,128] rm, W: [128,F] rm), hh = fp16(h).
// Block tile 64 x F, thread tile 4x8 (cols split tc*4 and tc*4+F/2 to keep
// LDS b-reads 2-way max). Threads = 16 * (F/8): 256 (F=128) / 128 (F=64).
// ---------------------------------------------------------------------------
template <int F>
__global__ __launch_bounds__(16 * (F / 8)) void gemm_alpha(
    const float* __restrict__ x, const float* __restrict__ W,
    const float* __restrict__ a_s, const float* __restrict__ a_d,
    __half* __restrict__ hh, float* __restrict__ alphaS, float* __restrict__ alphaD,
    int N)
{
    constexpr int K = 128;
    constexpr int BK = 32;
    constexpr int BM = 64;
    constexpr int TM = 4;
    constexpr int TN = 8;
    constexpr int TC = F / TN;           // 16 (F=128) or 8 (F=64)
    constexpr int THREADS = 16 * TC;

    __shared__ float As[BK][BM + 4];     // transposed x tile; reads: 4 bcast quads
    __shared__ float Bs[BK][F + 4];      // W tile; reads 2-way (free)

    const int tid = threadIdx.x;
    const int tr = tid / TC;             // 0..15
    const int tc = tid % TC;
    const int rowb = blockIdx.x * BM;
    const int c0 = tc * 4;               // first col group
    const int c1 = tc * 4 + F / 2;       // second col group

    float acc[TM][TN];
#pragma unroll
    for (int m = 0; m < TM; m++)
#pragma unroll
        for (int n = 0; n < TN; n++) acc[m][n] = 0.f;

    for (int kt = 0; kt < K / BK; kt++) {
        // stage x tile transposed: 8 lanes cover 128B contiguous per row
        for (int i = tid; i < BM * (BK / 4); i += THREADS) {
            int c4 = i & 7, r = i >> 3;
            int gr = rowb + r;
            float4 v = (gr < N) ? *(const float4*)(x + (size_t)gr * K + kt * BK + c4 * 4)
                                : make_float4(0.f, 0.f, 0.f, 0.f);
            As[c4 * 4 + 0][r] = v.x;
            As[c4 * 4 + 1][r] = v.y;
            As[c4 * 4 + 2][r] = v.z;
            As[c4 * 4 + 3][r] = v.w;
        }
        // stage W tile
        for (int i = tid; i < BK * (F / 4); i += THREADS) {
            int r = i / (F / 4), c4 = i % (F / 4);
            *(float4*)&Bs[r][c4 * 4] = *(const float4*)(W + (size_t)(kt * BK + r) * F + c4 * 4);
        }
        __syncthreads();

#pragma unroll 8
        for (int k = 0; k < BK; k++) {
            float a[TM], b[TN];
            *(float4*)&a[0] = *(float4*)&As[k][tr * 4];
            *(float4*)&b[0] = *(float4*)&Bs[k][c0];
            *(float4*)&b[4] = *(float4*)&Bs[k][c1];
#pragma unroll
            for (int m = 0; m < TM; m++)
#pragma unroll
                for (int n = 0; n < TN; n++)
                    acc[m][n] += a[m] * b[n];
        }
        __syncthreads();
    }

    float asv[TN], adv[TN];
    *(float4*)&asv[0] = *(const float4*)(a_s + c0);
    *(float4*)&asv[4] = *(const float4*)(a_s + c1);
    *(float4*)&adv[0] = *(const float4*)(a_d + c0);
    *(float4*)&adv[4] = *(const float4*)(a_d + c1);

#pragma unroll
    for (int m = 0; m < TM; m++) {
        int row = rowb + tr * 4 + m;
        bool ok = (row < N);
        if (ok) {
            __half2 h0 = __floats2half2_rn(acc[m][0], acc[m][1]);
            __half2 h1 = __floats2half2_rn(acc[m][2], acc[m][3]);
            __half2 h2 = __floats2half2_rn(acc[m][4], acc[m][5]);
            __half2 h3 = __floats2half2_rn(acc[m][6], acc[m][7]);
            __half2* hp0 = (__half2*)(hh + (size_t)row * F + c0);
            __half2* hp1 = (__half2*)(hh + (size_t)row * F + c1);
            hp0[0] = h0; hp0[1] = h1;
            hp1[0] = h2; hp1[1] = h3;
        }
        float ps = 0.f, pd = 0.f;
#pragma unroll
        for (int n = 0; n < TN; n++) {
            ps += acc[m][n] * asv[n];
            pd += acc[m][n] * adv[n];
        }
#pragma unroll
        for (int off = TC / 2; off >= 1; off >>= 1) {
            ps += __shfl_down(ps, off, TC);
            pd += __shfl_down(pd, off, TC);
        }
        if (ok && tc == 0) { alphaS[row] = ps; alphaD[row] = pd; }
    }
}

// ---------------------------------------------------------------------------
// CSR build: histogram, multi-block exclusive scan, scatter permutation.
// ---------------------------------------------------------------------------
__global__ __launch_bounds__(256) void hist_kernel(
    const int* __restrict__ dst, int* __restrict__ cnt, int E)
{
    int e = blockIdx.x * 256 + threadIdx.x;
    if (e < E) atomicAdd(cnt + dst[e], 1);
}

__global__ __launch_bounds__(256) void scan_bsum(
    const int* __restrict__ cnt, int* __restrict__ bsum, int N)
{
    int i = blockIdx.x * 256 + threadIdx.x;
    int v = (i < N) ? cnt[i] : 0;
#pragma unroll
    for (int off = 32; off; off >>= 1) v += __shfl_down(v, off);
    __shared__ int ws[4];
    int lane = threadIdx.x & 63, wid = threadIdx.x >> 6;
    if (lane == 0) ws[wid] = v;
    __syncthreads();
    if (threadIdx.x == 0) bsum[blockIdx.x] = ws[0] + ws[1] + ws[2] + ws[3];
}

__global__ __launch_bounds__(256) void scan_boff(
    const int* __restrict__ bsum, int* __restrict__ boff, int nb, int* __restrict__ totptr)
{
    __shared__ int ws[4];
    __shared__ int carry;
    int tid = threadIdx.x, lane = tid & 63, wid = tid >> 6;
    if (tid == 0) carry = 0;
    __syncthreads();
    for (int base = 0; base < nb; base += 256) {
        int i = base + tid;
        int v = (i < nb) ? bsum[i] : 0;
        int incl = wave_iscan(v, lane);
        if (lane == 63) ws[wid] = incl;
        __syncthreads();
        int woff = carry;
        for (int w = 0; w < wid; w++) woff += ws[w];
        if (i < nb) boff[i] = woff + incl - v;
        __syncthreads();
        if (tid == 0) carry += ws[0] + ws[1] + ws[2] + ws[3];
        __syncthreads();
    }
    if (tid == 0) *totptr = carry;
}

__global__ __launch_bounds__(256) void scan_final(
    const int* __restrict__ cnt, const int* __restrict__ boff,
    int* __restrict__ rowptr, int* __restrict__ fill, int N)
{
    int i = blockIdx.x * 256 + threadIdx.x;
    int v = (i < N) ? cnt[i] : 0;
    int lane = threadIdx.x & 63, wid = threadIdx.x >> 6;
    int incl = wave_iscan(v, lane);
    __shared__ int ws[4];
    if (lane == 63) ws[wid] = incl;
    __syncthreads();
    int woff = boff[blockIdx.x];
    for (int w = 0; w < wid; w++) woff += ws[w];
    int excl = woff + incl - v;
    if (i < N) { rowptr[i] = excl; fill[i] = excl; }
}

__global__ __launch_bounds__(256) void scatter_kernel(
    const int* __restrict__ src, const int* __restrict__ dst,
    int* __restrict__ fill, int* __restrict__ src_sorted, int E)
{
    int e = blockIdx.x * 256 + threadIdx.x;
    if (e < E) {
        int p = atomicAdd(fill + dst[e], 1);
        src_sorted[p] = src[e];
    }
}

// ---------------------------------------------------------------------------
// Fused per-destination aggregation (no atomics), fp16 message gather
// (8 B/lane), 2-wide edge unroll + cross-iteration src prefetch.
// ---------------------------------------------------------------------------
template <int F, bool RELU>
__global__ __launch_bounds__(256) void gat_aggregate(
    const int* __restrict__ rowptr, const int* __restrict__ src_sorted,
    const __half* __restrict__ hh, const float* __restrict__ aS,
    const float* __restrict__ aD, const float* __restrict__ bias,
    float* __restrict__ out, int N)
{
    constexpr int LPE = F / 4;          // lanes per edge (32 or 16)
    constexpr int EPW = 64 / LPE;       // edge slots per wave (2 or 4)

    const int i = blockIdx.x * 4 + (threadIdx.x >> 6);
    if (i >= N) return;
    const int lane = threadIdx.x & 63;
    const int sub = lane / LPE;
    const int l = lane % LPE;

    const float adi = aD[i];
    const int start = rowptr[i];
    const int end = rowptr[i + 1];

    float4 acc0 = make_float4(0.f, 0.f, 0.f, 0.f);
    float4 acc1 = make_float4(0.f, 0.f, 0.f, 0.f);
    float den0 = 0.f, den1 = 0.f;

    int e0 = start + sub;
    int e1 = e0 + EPW;
    int s0 = (e0 < end) ? src_sorted[e0] : -1;
    int s1 = (e1 < end) ? src_sorted[e1] : -1;

    while (e0 < end) {
        int n0 = (e0 + 2 * EPW < end) ? src_sorted[e0 + 2 * EPW] : -1;
        int n1 = (e1 + 2 * EPW < end) ? src_sorted[e1 + 2 * EPW] : -1;
        {
            float w = __expf(leaky(aS[s0] + adi));
            const __half2* hp = (const __half2*)(hh + (size_t)s0 * F) + l * 2;
            float2 f0 = __half22float2(hp[0]);
            float2 f1 = __half22float2(hp[1]);
            acc0.x += w * f0.x; acc0.y += w * f0.y;
            acc0.z += w * f1.x; acc0.w += w * f1.y;
            den0 += w;
        }
        if (s1 >= 0) {
            float w = __expf(leaky(aS[s1] + adi));
            const __half2* hp = (const __half2*)(hh + (size_t)s1 * F) + l * 2;
            float2 f0 = __half22float2(hp[0]);
            float2 f1 = __half22float2(hp[1]);
            acc1.x += w * f0.x; acc1.y += w * f0.y;
            acc1.z += w * f1.x; acc1.w += w * f1.y;
            den1 += w;
        }
        e0 += 2 * EPW; e1 += 2 * EPW;
        s0 = n0; s1 = n1;
        if (s0 < 0) break;
    }

    float4 acc = make_float4(acc0.x + acc1.x, acc0.y + acc1.y,
                             acc0.z + acc1.z, acc0.w + acc1.w);
    float denom = den0 + den1;

#pragma unroll
    for (int off = 32; off >= LPE; off >>= 1) {
        acc.x += __shfl_down(acc.x, off);
        acc.y += __shfl_down(acc.y, off);
        acc.z += __shfl_down(acc.z, off);
        acc.w += __shfl_down(acc.w, off);
        denom += __shfl_down(denom, off);
    }

    if (sub == 0) {
        float wsf = __expf(leaky(aS[i] + adi));
        const __half2* hp = (const __half2*)(hh + (size_t)i * F) + l * 2;
        float2 f0 = __half22float2(hp[0]);
        float2 f1 = __half22float2(hp[1]);
        float inv = 1.f / (denom + wsf);
        float4 bv = *(const float4*)(bias + l * 4);
        float4 o;
        o.x = (acc.x + wsf * f0.x) * inv + bv.x;
        o.y = (acc.y + wsf * f0.y) * inv + bv.y;
        o.z = (acc.z + wsf * f1.x) * inv + bv.z;
        o.w = (acc.w + wsf * f1.y) * inv + bv.w;
        if (RELU) {
            o.x = fmaxf(o.x, 0.f); o.y = fmaxf(o.y, 0.f);
            o.z = fmaxf(o.z, 0.f); o.w = fmaxf(o.w, 0.f);
        }
        *(float4*)(out + (size_t)i * F + l * 4) = o;
    }
}

extern "C" void kernel_launch(void* const* d_in, const int* in_sizes, int n_in,
                              void* d_out, int out_size, void* d_ws, size_t ws_size,
                              hipStream_t stream)
{
    const float* x   = (const float*)d_in[0];
    const int*   ei  = (const int*)d_in[1];
    const float* W1  = (const float*)d_in[2];
    const float* aS1 = (const float*)d_in[3];
    const float* aD1 = (const float*)d_in[4];
    const float* b1  = (const float*)d_in[5];
    const float* W2  = (const float*)d_in[6];
    const float* aS2 = (const float*)d_in[7];
    const float* aD2 = (const float*)d_in[8];
    const float* b2  = (const float*)d_in[9];

    const int K = 128, F1 = 128, F2 = 64;
    const int N = in_sizes[0] / K;
    const int E = in_sizes[1] / 2;
    const int* src = ei;
    const int* dst = ei + E;

    const int Np = (N + 4) & ~3;
    const int nb = (N + 255) / 256;

    char* wsb = (char*)d_ws;
    int* cnt        = (int*)wsb;    wsb += (size_t)Np * 4;          // zeroed
    int* rowptr     = (int*)wsb;    wsb += (size_t)(Np + 4) * 4;
    int* fill       = (int*)wsb;    wsb += (size_t)Np * 4;
    int* bsum       = (int*)wsb;    wsb += 1024 * 4;
    int* boff       = (int*)wsb;    wsb += 1024 * 4;
    int* src_sorted = (int*)wsb;    wsb += (size_t)E * 4;
    __half* hh1     = (__half*)wsb; wsb += (size_t)N * F1 * 2;
    __half* hh2     = (__half*)wsb; wsb += (size_t)N * F2 * 2;
    float* x2       = (float*)wsb;  wsb += (size_t)N * F1 * 4;
    float* as_      = (float*)wsb;  wsb += (size_t)Np * 4;
    float* ad_      = (float*)wsb;  wsb += (size_t)Np * 4;

    hipMemsetAsync(cnt, 0, (size_t)Np * 4, stream);

    dim3 blk(256);

    // ---- CSR build ----
    hist_kernel<<<dim3((E + 255) / 256), blk, 0, stream>>>(dst, cnt, E);
    scan_bsum<<<dim3(nb), blk, 0, stream>>>(cnt, bsum, N);
    scan_boff<<<dim3(1), blk, 0, stream>>>(bsum, boff, nb, rowptr + N);
    scan_final<<<dim3(nb), blk, 0, stream>>>(cnt, boff, rowptr, fill, N);
    scatter_kernel<<<dim3((E + 255) / 256), blk, 0, stream>>>(src, dst, fill, src_sorted, E);

    // ---- layer 1 ----
    gemm_alpha<F1><<<dim3((N + 63) / 64), dim3(256), 0, stream>>>(
        x, W1, aS1, aD1, hh1, as_, ad_, N);
    gat_aggregate<F1, true><<<dim3((N + 3) / 4), blk, 0, stream>>>(
        rowptr, src_sorted, hh1, as_, ad_, b1, x2, N);

    // ---- layer 2 ----
    gemm_alpha<F2><<<dim3((N + 63) / 64), dim3(128), 0, stream>>>(
        x2, W2, aS2, aD2, hh2, as_, ad_, N);
    gat_aggregate<F2, false><<<dim3((N + 3) / 4), blk, 0, stream>>>(
        rowptr, src_sorted, hh2, as_, ad_, b2, (float*)d_out, N);
}

// Round 5
// 230.653 us; speedup vs baseline: 9.9172x; 1.2807x over previous
//
#include <hip/hip_runtime.h>
#include <hip/hip_fp16.h>
#include <cstddef>

#define NEG_SLOPE 0.2f
#define TILE 4096

__device__ __forceinline__ float leaky(float x) { return x >= 0.f ? x : NEG_SLOPE * x; }

__device__ __forceinline__ int wave_iscan(int v, int lane) {
#pragma unroll
    for (int off = 1; off < 64; off <<= 1) {
        int t = __shfl_up(v, off);
        if (lane >= off) v += t;
    }
    return v;
}

// ---------------------------------------------------------------------------
// Register-blocked SGEMM + fused alpha dots, fp16 output for message gather.
// ---------------------------------------------------------------------------
template <int F>
__global__ __launch_bounds__(16 * (F / 8)) void gemm_alpha(
    const float* __restrict__ x, const float* __restrict__ W,
    const float* __restrict__ a_s, const float* __restrict__ a_d,
    __half* __restrict__ hh, float* __restrict__ alphaS, float* __restrict__ alphaD,
    int N)
{
    constexpr int K = 128;
    constexpr int BK = 32;
    constexpr int BM = 64;
    constexpr int TM = 4;
    constexpr int TN = 8;
    constexpr int TC = F / TN;
    constexpr int THREADS = 16 * TC;

    __shared__ float As[BK][BM + 4];
    __shared__ float Bs[BK][F + 4];

    const int tid = threadIdx.x;
    const int tr = tid / TC;
    const int tc = tid % TC;
    const int rowb = blockIdx.x * BM;
    const int c0 = tc * 4;
    const int c1 = tc * 4 + F / 2;

    float acc[TM][TN];
#pragma unroll
    for (int m = 0; m < TM; m++)
#pragma unroll
        for (int n = 0; n < TN; n++) acc[m][n] = 0.f;

    for (int kt = 0; kt < K / BK; kt++) {
        for (int i = tid; i < BM * (BK / 4); i += THREADS) {
            int c4 = i & 7, r = i >> 3;
            int gr = rowb + r;
            float4 v = (gr < N) ? *(const float4*)(x + (size_t)gr * K + kt * BK + c4 * 4)
                                : make_float4(0.f, 0.f, 0.f, 0.f);
            As[c4 * 4 + 0][r] = v.x;
            As[c4 * 4 + 1][r] = v.y;
            As[c4 * 4 + 2][r] = v.z;
            As[c4 * 4 + 3][r] = v.w;
        }
        for (int i = tid; i < BK * (F / 4); i += THREADS) {
            int r = i / (F / 4), c4 = i % (F / 4);
            *(float4*)&Bs[r][c4 * 4] = *(const float4*)(W + (size_t)(kt * BK + r) * F + c4 * 4);
        }
        __syncthreads();

#pragma unroll 8
        for (int k = 0; k < BK; k++) {
            float a[TM], b[TN];
            *(float4*)&a[0] = *(float4*)&As[k][tr * 4];
            *(float4*)&b[0] = *(float4*)&Bs[k][c0];
            *(float4*)&b[4] = *(float4*)&Bs[k][c1];
#pragma unroll
            for (int m = 0; m < TM; m++)
#pragma unroll
                for (int n = 0; n < TN; n++)
                    acc[m][n] += a[m] * b[n];
        }
        __syncthreads();
    }

    float asv[TN], adv[TN];
    *(float4*)&asv[0] = *(const float4*)(a_s + c0);
    *(float4*)&asv[4] = *(const float4*)(a_s + c1);
    *(float4*)&adv[0] = *(const float4*)(a_d + c0);
    *(float4*)&adv[4] = *(const float4*)(a_d + c1);

#pragma unroll
    for (int m = 0; m < TM; m++) {
        int row = rowb + tr * 4 + m;
        bool ok = (row < N);
        if (ok) {
            __half2 h0 = __floats2half2_rn(acc[m][0], acc[m][1]);
            __half2 h1 = __floats2half2_rn(acc[m][2], acc[m][3]);
            __half2 h2 = __floats2half2_rn(acc[m][4], acc[m][5]);
            __half2 h3 = __floats2half2_rn(acc[m][6], acc[m][7]);
            __half2* hp0 = (__half2*)(hh + (size_t)row * F + c0);
            __half2* hp1 = (__half2*)(hh + (size_t)row * F + c1);
            hp0[0] = h0; hp0[1] = h1;
            hp1[0] = h2; hp1[1] = h3;
        }
        float ps = 0.f, pd = 0.f;
#pragma unroll
        for (int n = 0; n < TN; n++) {
            ps += acc[m][n] * asv[n];
            pd += acc[m][n] * adv[n];
        }
#pragma unroll
        for (int off = TC / 2; off >= 1; off >>= 1) {
            ps += __shfl_down(ps, off, TC);
            pd += __shfl_down(pd, off, TC);
        }
        if (ok && tc == 0) { alphaS[row] = ps; alphaD[row] = pd; }
    }
}

// ---------------------------------------------------------------------------
// CSR build via 2-level bucket sort (bucket = dst>>8). All scatter writes are
// either LDS-grouped contiguous runs or block-exclusive L2-local regions.
// ---------------------------------------------------------------------------
__global__ __launch_bounds__(256) void bucket_count(
    const int* __restrict__ dst, int* __restrict__ gcnt, int E)
{
    __shared__ int lcnt[256];
    const int tid = threadIdx.x;
    const int base = blockIdx.x * TILE;
    lcnt[tid] = 0;
    __syncthreads();
#pragma unroll
    for (int j = 0; j < TILE / 256; j++) {
        int idx = base + j * 256 + tid;
        if (idx < E) atomicAdd(&lcnt[dst[idx] >> 8], 1);
    }
    __syncthreads();
    int c = lcnt[tid];
    if (c > 0) atomicAdd(&gcnt[tid], c);
}

__global__ __launch_bounds__(256) void bucket_scan(
    const int* __restrict__ gcnt, int* __restrict__ gstart,
    int* __restrict__ gfill, int NB, int* __restrict__ rowptrN, int E)
{
    __shared__ int ws[4];
    int tid = threadIdx.x, lane = tid & 63, wid = tid >> 6;
    int v = (tid < NB) ? gcnt[tid] : 0;
    int incl = wave_iscan(v, lane);
    if (lane == 63) ws[wid] = incl;
    __syncthreads();
    int woff = 0;
    for (int w = 0; w < wid; w++) woff += ws[w];
    int excl = woff + incl - v;
    if (tid <= NB) gstart[tid] = excl;
    if (tid < NB) gfill[tid] = excl;
    if (tid == 0) *rowptrN = E;
}

__global__ __launch_bounds__(256) void bucket_scatter(
    const int* __restrict__ src, const int* __restrict__ dst,
    int* __restrict__ gfill, uint2* __restrict__ staging, int E)
{
    __shared__ int lcnt[256];
    __shared__ int loff[256];
    __shared__ int gbase[256];
    __shared__ int ws[4];
    __shared__ uint2 pairs[TILE];
    __shared__ unsigned char bkt[TILE];

    const int tid = threadIdx.x;
    const int base = blockIdx.x * TILE;
    const int vt = min(TILE, E - base);

    lcnt[tid] = 0;
    __syncthreads();

    int d[TILE / 256], s[TILE / 256], r[TILE / 256];
#pragma unroll
    for (int j = 0; j < TILE / 256; j++) {
        int idx = base + j * 256 + tid;
        if (idx < E) {
            d[j] = dst[idx]; s[j] = src[idx];
            r[j] = atomicAdd(&lcnt[d[j] >> 8], 1);
        } else d[j] = -1;
    }
    __syncthreads();
    {
        int lane = tid & 63, wid = tid >> 6;
        int v = lcnt[tid];
        int incl = wave_iscan(v, lane);
        if (lane == 63) ws[wid] = incl;
        __syncthreads();
        int woff = 0;
        for (int w = 0; w < wid; w++) woff += ws[w];
        loff[tid] = woff + incl - v;
    }
    __syncthreads();
    {
        int c = lcnt[tid];
        if (c > 0) gbase[tid] = atomicAdd(&gfill[tid], c);
    }
    __syncthreads();
#pragma unroll
    for (int j = 0; j < TILE / 256; j++) {
        if (d[j] >= 0) {
            int b = d[j] >> 8;
            int slot = loff[b] + r[j];
            pairs[slot] = make_uint2((unsigned)d[j], (unsigned)s[j]);
            bkt[slot] = (unsigned char)b;
        }
    }
    __syncthreads();
    for (int slot = tid; slot < vt; slot += 256) {
        int b = bkt[slot];
        staging[gbase[b] + (slot - loff[b])] = pairs[slot];
    }
}

__global__ __launch_bounds__(256) void bucket_to_csr(
    const uint2* __restrict__ staging, const int* __restrict__ gstart,
    int* __restrict__ rowptr, int* __restrict__ src_sorted, int N)
{
    __shared__ int lcnt[256], loff[256], lfill[256];
    __shared__ int ws[4];
    const int tid = threadIdx.x;
    const int b = blockIdx.x;
    const int beg = gstart[b], end = gstart[b + 1];

    lcnt[tid] = 0;
    __syncthreads();
    for (int idx = beg + tid; idx < end; idx += 256)
        atomicAdd(&lcnt[staging[idx].x & 255], 1);
    __syncthreads();
    {
        int lane = tid & 63, wid = tid >> 6;
        int v = lcnt[tid];
        int incl = wave_iscan(v, lane);
        if (lane == 63) ws[wid] = incl;
        __syncthreads();
        int woff = 0;
        for (int w = 0; w < wid; w++) woff += ws[w];
        int excl = woff + incl - v;
        loff[tid] = excl;
        lfill[tid] = excl;
        int node = (b << 8) + tid;
        if (node < N) rowptr[node] = beg + excl;
    }
    __syncthreads();
    for (int idx = beg + tid; idx < end; idx += 256) {
        uint2 p = staging[idx];
        int pos = atomicAdd(&lfill[p.x & 255], 1);
        src_sorted[beg + pos] = (int)p.y;   // block-exclusive 16KB region: L2-local
    }
}

// ---------------------------------------------------------------------------
// Fused per-destination aggregation: fp16 gather 16 B/lane, LPE=F/8 lanes per
// edge, EPW edge slots per wave, 2-wide unroll + src prefetch.
// ---------------------------------------------------------------------------
template <int F, bool RELU>
__global__ __launch_bounds__(256) void gat_aggregate(
    const int* __restrict__ rowptr, const int* __restrict__ src_sorted,
    const __half* __restrict__ hh, const float* __restrict__ aS,
    const float* __restrict__ aD, const float* __restrict__ bias,
    float* __restrict__ out, int N)
{
    constexpr int LPE = F / 8;          // lanes per edge (16 or 8)
    constexpr int EPW = 64 / LPE;       // edge slots per wave (4 or 8)

    const int i = blockIdx.x * 4 + (threadIdx.x >> 6);
    if (i >= N) return;
    const int lane = threadIdx.x & 63;
    const int sub = lane / LPE;
    const int l = lane % LPE;

    const float adi = aD[i];
    const int start = rowptr[i];
    const int end = rowptr[i + 1];

    float acc0[8], acc1[8];
#pragma unroll
    for (int q = 0; q < 8; q++) { acc0[q] = 0.f; acc1[q] = 0.f; }
    float den0 = 0.f, den1 = 0.f;

    int e0 = start + sub;
    int e1 = e0 + EPW;
    int s0 = (e0 < end) ? src_sorted[e0] : -1;
    int s1 = (e1 < end) ? src_sorted[e1] : -1;

    while (s0 >= 0) {
        int n0 = (e0 + 2 * EPW < end) ? src_sorted[e0 + 2 * EPW] : -1;
        int n1 = (e1 + 2 * EPW < end) ? src_sorted[e1 + 2 * EPW] : -1;
        {
            float w = __expf(leaky(aS[s0] + adi));
            uint4 u = *(const uint4*)(hh + (size_t)s0 * F + l * 8);
            const __half2* hp = (const __half2*)&u;
#pragma unroll
            for (int q = 0; q < 4; q++) {
                float2 f = __half22float2(hp[q]);
                acc0[q * 2]     += w * f.x;
                acc0[q * 2 + 1] += w * f.y;
            }
            den0 += w;
        }
        if (s1 >= 0) {
            float w = __expf(leaky(aS[s1] + adi));
            uint4 u = *(const uint4*)(hh + (size_t)s1 * F + l * 8);
            const __half2* hp = (const __half2*)&u;
#pragma unroll
            for (int q = 0; q < 4; q++) {
                float2 f = __half22float2(hp[q]);
                acc1[q * 2]     += w * f.x;
                acc1[q * 2 + 1] += w * f.y;
            }
            den1 += w;
        }
        e0 += 2 * EPW; e1 += 2 * EPW;
        s0 = n0; s1 = n1;
    }

    float acc[8];
#pragma unroll
    for (int q = 0; q < 8; q++) acc[q] = acc0[q] + acc1[q];
    float denom = den0 + den1;

#pragma unroll
    for (int off = 32; off >= LPE; off >>= 1) {
#pragma unroll
        for (int q = 0; q < 8; q++) acc[q] += __shfl_down(acc[q], off);
        denom += __shfl_down(denom, off);
    }

    if (sub == 0) {
        float wsf = __expf(leaky(aS[i] + adi));
        uint4 u = *(const uint4*)(hh + (size_t)i * F + l * 8);
        const __half2* hp = (const __half2*)&u;
        float inv = 1.f / (denom + wsf);
        float4 b0 = *(const float4*)(bias + l * 8);
        float4 b1 = *(const float4*)(bias + l * 8 + 4);
        float o[8];
#pragma unroll
        for (int q = 0; q < 4; q++) {
            float2 f = __half22float2(hp[q]);
            o[q * 2]     = (acc[q * 2]     + wsf * f.x) * inv;
            o[q * 2 + 1] = (acc[q * 2 + 1] + wsf * f.y) * inv;
        }
        o[0] += b0.x; o[1] += b0.y; o[2] += b0.z; o[3] += b0.w;
        o[4] += b1.x; o[5] += b1.y; o[6] += b1.z; o[7] += b1.w;
        if (RELU) {
#pragma unroll
            for (int q = 0; q < 8; q++) o[q] = fmaxf(o[q], 0.f);
        }
        *(float4*)(out + (size_t)i * F + l * 8)     = make_float4(o[0], o[1], o[2], o[3]);
        *(float4*)(out + (size_t)i * F + l * 8 + 4) = make_float4(o[4], o[5], o[6], o[7]);
    }
}

extern "C" void kernel_launch(void* const* d_in, const int* in_sizes, int n_in,
                              void* d_out, int out_size, void* d_ws, size_t ws_size,
                              hipStream_t stream)
{
    const float* x   = (const float*)d_in[0];
    const int*   ei  = (const int*)d_in[1];
    const float* W1  = (const float*)d_in[2];
    const float* aS1 = (const float*)d_in[3];
    const float* aD1 = (const float*)d_in[4];
    const float* b1  = (const float*)d_in[5];
    const float* W2  = (const float*)d_in[6];
    const float* aS2 = (const float*)d_in[7];
    const float* aD2 = (const float*)d_in[8];
    const float* b2  = (const float*)d_in[9];

    const int K = 128, F1 = 128, F2 = 64;
    const int N = in_sizes[0] / K;
    const int E = in_sizes[1] / 2;
    const int* src = ei;
    const int* dst = ei + E;

    const int Np = (N + 4) & ~3;
    const int NB = (N + 255) >> 8;          // 196 buckets
    const int nbt = (E + TILE - 1) / TILE;  // tiles over edges

    char* wsb = (char*)d_ws;
    int* gcnt       = (int*)wsb;    wsb += 256 * 4;                 // zeroed
    int* gstart     = (int*)wsb;    wsb += 264 * 4;
    int* gfill      = (int*)wsb;    wsb += 256 * 4;
    int* rowptr     = (int*)wsb;    wsb += (size_t)(Np + 4) * 4;
    uint2* staging  = (uint2*)wsb;  wsb += (size_t)E * 8;
    int* src_sorted = (int*)wsb;    wsb += (size_t)E * 4;
    __half* hh1     = (__half*)wsb; wsb += (size_t)N * F1 * 2;
    __half* hh2     = (__half*)wsb; wsb += (size_t)N * F2 * 2;
    float* x2       = (float*)wsb;  wsb += (size_t)N * F1 * 4;
    float* as_      = (float*)wsb;  wsb += (size_t)Np * 4;
    float* ad_      = (float*)wsb;  wsb += (size_t)Np * 4;

    hipMemsetAsync(gcnt, 0, 256 * 4, stream);

    dim3 blk(256);

    // ---- CSR build (bucketed, write-local) ----
    bucket_count<<<dim3(nbt), blk, 0, stream>>>(dst, gcnt, E);
    bucket_scan<<<dim3(1), blk, 0, stream>>>(gcnt, gstart, gfill, NB, rowptr + N, E);
    bucket_scatter<<<dim3(nbt), blk, 0, stream>>>(src, dst, gfill, staging, E);
    bucket_to_csr<<<dim3(NB), blk, 0, stream>>>(staging, gstart, rowptr, src_sorted, N);

    // ---- layer 1 ----
    gemm_alpha<F1><<<dim3((N + 63) / 64), dim3(256), 0, stream>>>(
        x, W1, aS1, aD1, hh1, as_, ad_, N);
    gat_aggregate<F1, true><<<dim3((N + 3) / 4), blk, 0, stream>>>(
        rowptr, src_sorted, hh1, as_, ad_, b1, x2, N);

    // ---- layer 2 ----
    gemm_alpha<F2><<<dim3((N + 63) / 64), dim3(128), 0, stream>>>(
        x2, W2, aS2, aD2, hh2, as_, ad_, N);
    gat_aggregate<F2, false><<<dim3((N + 3) / 4), blk, 0, stream>>>(
        rowptr, src_sorted, hh2, as_, ad_, b2, (float*)d_out, N);
}